// Round 1
// baseline (218.254 us; speedup 1.0000x reference)
//
#include <hip/hip_runtime.h>

#define CROPX 512
#define NN 510          // CROP - 2
#define BATCHX 32

constexpr float INV_DX   = 100.0f;     // 1/DX
constexpr float DT_F     = 0.001f;
constexpr float INV_DXDT = 100000.0f;  // 1/(DX*DT)
constexpr float INV_DX2  = 10000.0f;   // 1/DX^2

#define IX(r,c) ((r)*CROPX + (c))

// -------------------- main interior kernel --------------------
// grid: (2 colgroups, 16 row tiles, 32 batches), 256 threads.
// Thread owns one output column b, loops over output rows a in its tile.
// Carried registers: FN_u(a,1+b), FN_v(a,1+b), dvdt(a-1,b), pp(a,1+b), pp(1+a,1+b), v[a,1+b].
__global__ __launch_bounds__(256) void pde_main(const float* __restrict__ g,
                                                const float* __restrict__ png,
                                                float* __restrict__ ws) {
    const int bb   = blockIdx.z;
    const int tile = blockIdx.y;          // 0..15
    const int cg   = blockIdx.x;          // 0..1
    const int t    = threadIdx.x;
    const int lane = t & 63;

    const int borig  = cg * 256 + t;      // 0..511
    const bool active = (borig < NN);     // interior cols: 0..509
    const int b = active ? borig : (NN - 1);   // clamp inactive lanes in-bounds

    const int a0 = tile * 32;
    const int a1 = (a0 + 32 < NN) ? (a0 + 32) : NN;

    const float* u  = g + (size_t)bb * 3 * (CROPX * CROPX);
    const float* v  = u + CROPX * CROPX;
    const float* p  = v + CROPX * CROPX;
    const float* pn = png + (size_t)bb * (CROPX * CROPX);

    // ---- warm-up carried state for iteration a = a0 ----
    float fnu_c, fnv_c, dvdt_c, ppN, ppC, v_up;
    {
        const int j = b + 1;                       // 1+b
        float u_a_j  = u[IX(a0, j)];
        float u_a1_j = u[IX(a0 + 1, j)];
        float v_a_j  = v[IX(a0, j)];
        float v_a_j1 = v[IX(a0, j + 1)];
        float v_a1_j = v[IX(a0 + 1, j)];
        // FN_u(a0,1+b) = avg_x(v)*avg_y(u) - (u[a0+1]-u[a0])
        fnu_c = 0.5f * (v_a_j + v_a_j1) * 0.5f * (u_a_j + u_a1_j) - (u_a1_j - u_a_j);
        float vy = 0.5f * (v_a_j + v_a1_j);
        fnv_c = vy * vy - (v_a1_j - v_a_j);
        float p_a_j  = p[IX(a0, j)];
        float p_a1_j = p[IX(a0 + 1, j)];
        ppN = pn[IX(a0, j)] - p_a_j;               // pp(a0, 1+b)
        ppC = pn[IX(a0 + 1, j)] - p_a1_j;          // pp(1+a0, 1+b)
        v_up = v_a_j;                              // v[a0, 1+b]
        dvdt_c = 0.0f;
        if (a0 > 0) {
            // dvdt(a0-1, b) = -(FEv(a0,1+b)-FEv(a0,b)) - (FNv(a0,1+b)-FNv(a0-1,1+b)) - (p[a0+1,1+b]-p[a0,1+b]) all /DX
            float u_a_b  = u[IX(a0, b)];
            float u_a1_b = u[IX(a0 + 1, b)];
            float v_a_b  = v[IX(a0, b)];
            float fev_b = 0.5f * (u_a_b + u_a1_b) * 0.5f * (v_a_b + v_a_j) - (v_a_j - v_a_b);
            float fev_j = 0.5f * (u_a_j + u_a1_j) * 0.5f * (v_a_j + v_a_j1) - (v_a_j1 - v_a_j);
            float v_am1_j = v[IX(a0 - 1, j)];
            float vym = 0.5f * (v_am1_j + v_a_j);
            float fnv_m = vym * vym - (v_a_j - v_am1_j);
            dvdt_c = (-(fev_j - fev_b) - (fnv_c - fnv_m) - (p_a1_j - p_a_j)) * INV_DX;
        }
    }

    float cont_acc = 0.0f, pois_acc = 0.0f;

    for (int a = a0; a < a1; ++a) {
        const int r1 = a + 1, r2 = a + 2;
        float u1_0 = u[IX(r1, b)],  u1_1 = u[IX(r1, b + 1)], u1_2 = u[IX(r1, b + 2)];
        float u2_0 = u[IX(r2, b)],  u2_1 = u[IX(r2, b + 1)];
        float v1_0 = v[IX(r1, b)],  v1_1 = v[IX(r1, b + 1)], v1_2 = v[IX(r1, b + 2)];
        float v2_1 = v[IX(r2, b + 1)];
        float p1_0 = p[IX(r1, b)],  p1_1 = p[IX(r1, b + 1)], p1_2 = p[IX(r1, b + 2)];
        float p2_1 = p[IX(r2, b + 1)];
        float pn1_0 = pn[IX(r1, b)], pn1_2 = pn[IX(r1, b + 2)], pn2_1 = pn[IX(r2, b + 1)];

        // fluxes on row r1 = 1+a (VISC/DX == 1.0)
        float ux_b  = 0.5f * (u1_0 + u1_1), ux_b1 = 0.5f * (u1_1 + u1_2);
        float feu_b  = ux_b  * ux_b  - (u1_1 - u1_0);     // FE_u(1+a, b)
        float feu_b1 = ux_b1 * ux_b1 - (u1_2 - u1_1);     // FE_u(1+a, 1+b)
        float vx_b  = 0.5f * (v1_0 + v1_1), vx_b1 = 0.5f * (v1_1 + v1_2);
        float uy_b  = 0.5f * (u1_0 + u2_0), uy_b1 = 0.5f * (u1_1 + u2_1);
        float prod_b = uy_b * vx_b, prod_b1 = uy_b1 * vx_b1;
        float fnu_b1 = prod_b1 - (u2_1 - u1_1);           // FN_u(1+a, 1+b)
        float fev_b  = prod_b  - (v1_1 - v1_0);           // FE_v(1+a, b)
        float fev_b1 = prod_b1 - (v1_2 - v1_1);           // FE_v(1+a, 1+b)
        float vy_b1 = 0.5f * (v1_1 + v2_1);
        float fnv_b1 = vy_b1 * vy_b1 - (v2_1 - v1_1);     // FN_v(1+a, 1+b)

        float dudt_b = (-(feu_b1 - feu_b) - (fnu_b1 - fnu_c) - (p1_2 - p1_1)) * INV_DX; // dudt(a,b)
        float dvdt_b = (-(fev_b1 - fev_b) - (fnv_b1 - fnv_c) - (p2_1 - p1_1)) * INV_DX; // dvdt(a,b)

        // dudt(a, b-1): from left lane; lane 0 recomputes directly
        float dudtL = __shfl_up(dudt_b, 1, 64);
        if (lane == 0 && b >= 1) {
            float um1 = u[IX(r1, b - 1)];
            float ux_m = 0.5f * (um1 + u1_0);
            float feu_m = ux_m * ux_m - (u1_0 - um1);               // FE_u(1+a, b-1)
            float fnu_b0 = prod_b - (u2_0 - u1_0);                  // FN_u(1+a, b)
            float ua0 = u[IX(a, b)], va0 = v[IX(a, b)], va1 = v[IX(a, b + 1)];
            float fnu_a = 0.5f * (va0 + va1) * 0.5f * (ua0 + u1_0) - (u1_0 - ua0); // FN_u(a, b)
            dudtL = (-(feu_b - feu_m) - (fnu_b0 - fnu_a) - (p1_1 - p1_0)) * INV_DX;
        }

        // p' cross (pp = p_next - p)
        float ppS = pn2_1 - p2_1;     // pp(2+a, 1+b)
        float ppW = pn1_0 - p1_0;     // pp(1+a, b)
        float ppE = pn1_2 - p1_2;     // pp(1+a, 2+b)
        float lap = 4.0f * ppC - ppE - ppW - ppS - ppN;

        float du_x = u1_1 - u1_0;
        float dv_y = v1_1 - v_up;

        // zero-padding masks of dudt_pad / dvdt_pad
        float dR = (b <= NN - 2) ? dudt_b : 0.0f;
        float dL = (b >= 1)      ? dudtL  : 0.0f;
        float vC = (a <= NN - 2) ? dvdt_b : 0.0f;
        float vP = (a >= 1)      ? dvdt_c : 0.0f;

        float bconv = (du_x + dv_y + DT_F * ((dR - dL) + (vC - vP))) * INV_DXDT;
        float pois  = lap * INV_DX2 + bconv;

        if (active) {
            cont_acc += fabsf((du_x + dv_y) * INV_DX);
            pois_acc += fabsf(pois);
        }

        // rotate carries
        fnu_c = fnu_b1; fnv_c = fnv_b1; dvdt_c = dvdt_b;
        ppN = ppC; ppC = ppS; v_up = v1_1;
    }

    // ---- block reduction + atomics ----
    __shared__ float sred[8];
    float c = cont_acc, q = pois_acc;
    for (int off = 32; off > 0; off >>= 1) {
        c += __shfl_down(c, off, 64);
        q += __shfl_down(q, off, 64);
    }
    int wid = t >> 6;
    if (lane == 0) { sred[wid] = c; sred[4 + wid] = q; }
    __syncthreads();
    if (t == 0) {
        float cs = sred[0] + sred[1] + sred[2] + sred[3];
        float qs = sred[4] + sred[5] + sred[6] + sred[7];
        atomicAdd(&ws[0], cs);
        atomicAdd(&ws[1], qs);
    }
}

// -------------------- boundary-condition kernel --------------------
// One block per batch: per-batch sums must complete BEFORE abs().
__global__ __launch_bounds__(256) void pde_bc(const float* __restrict__ g,
                                              float* __restrict__ ws) {
    const int bb = blockIdx.x;
    const int t  = threadIdx.x;
    const int lane = t & 63;
    const float* u = g + (size_t)bb * 3 * (CROPX * CROPX);
    const float* v = u + CROPX * CROPX;
    const float* p = v + CROPX * CROPX;

    float y0 = 0.0f, yL = 0.0f, x0 = 0.0f, xL = 0.0f;
    for (int j = 1 + t; j <= NN; j += 256) {          // j = 1..510
        if (j <= NN - 1) {                            // j = 1..509
            y0 += u[IX(0, j)] + u[IX(1, j)];
            yL += 2.0f - (u[IX(NN, j)] + u[IX(NN + 1, j)]);   // 2*U0
            x0 += v[IX(j, 0)] + v[IX(j, 1)];
            xL += v[IX(j, CROPX - 1)] + v[IX(j, CROPX - 2)];
        }
        y0 += v[IX(0, j)] + p[IX(0, j)];
        yL += v[IX(NN + 1, j)] + p[IX(NN + 1, j)];
        x0 += u[IX(j, 0)] + p[IX(j, 0)];
        xL += u[IX(j, CROPX - 1)] + p[IX(j, CROPX - 1)];
    }

    __shared__ float s4[4][4];
    for (int off = 32; off > 0; off >>= 1) {
        y0 += __shfl_down(y0, off, 64);
        yL += __shfl_down(yL, off, 64);
        x0 += __shfl_down(x0, off, 64);
        xL += __shfl_down(xL, off, 64);
    }
    int wid = t >> 6;
    if (lane == 0) { s4[wid][0] = y0; s4[wid][1] = yL; s4[wid][2] = x0; s4[wid][3] = xL; }
    __syncthreads();
    if (t == 0) {
        float Y0 = s4[0][0] + s4[1][0] + s4[2][0] + s4[3][0];
        float YL = s4[0][1] + s4[1][1] + s4[2][1] + s4[3][1];
        float X0 = s4[0][2] + s4[1][2] + s4[2][2] + s4[3][2];
        float XL = s4[0][3] + s4[1][3] + s4[2][3] + s4[3][3];
        atomicAdd(&ws[2], fabsf(Y0) + fabsf(YL) + fabsf(X0) + fabsf(XL));
    }
}

// -------------------- final combine --------------------
__global__ void pde_final(const float* __restrict__ ws, float* __restrict__ out) {
    if (threadIdx.x == 0 && blockIdx.x == 0) {
        const float inv = 1.0f / (float)(BATCHX * NN * NN);
        out[0] = 0.4f * ws[0] * inv + 0.4f * ws[1] * inv + 0.2f * ws[2];
    }
}

extern "C" void kernel_launch(void* const* d_in, const int* in_sizes, int n_in,
                              void* d_out, int out_size, void* d_ws, size_t ws_size,
                              hipStream_t stream) {
    const float* g  = (const float*)d_in[0];   // gen_output (32,3,512,512) f32
    const float* pn = (const float*)d_in[1];   // p_next_step (32,1,512,512) f32
    float* out = (float*)d_out;
    float* ws  = (float*)d_ws;

    hipMemsetAsync(ws, 0, 3 * sizeof(float), stream);

    dim3 grid(2, 16, 32);   // colgroups, row tiles, batches
    pde_main<<<grid, 256, 0, stream>>>(g, pn, ws);
    pde_bc<<<32, 256, 0, stream>>>(g, ws);
    pde_final<<<1, 64, 0, stream>>>(ws, out);
}